// Round 4
// baseline (2443.468 us; speedup 1.0000x reference)
//
#include <hip/hip_runtime.h>
#include <math.h>

// Problem constants (B,T,D) = (16,1024,1024)
#define BB 16
#define TT 1024
#define DD 1024
#define M_TOT (BB * TT)   // 16384 GEMM rows / LIF chains

typedef double v4d __attribute__((ext_vector_type(4)));
typedef double v2d __attribute__((ext_vector_type(2)));

#define CNOISE (0.005 * 0.15)   // NOISE_SCALE * THRESHOLD

// ---------------- Fast branch-free fp64 tanh ----------------
// tanh(y) = 1 - 2/(2^(y*2*log2(e)) + 1). Absolute error ~1e-15. Only ABSOLUTE
// ic accuracy (~1e-10) matters for spike thresholding. ~35 straight-line fp64
// ops vs libm's branchy ~80.
__device__ __forceinline__ double fast_tanh64(double y) {
    double z = y * 2.8853900817779268;              // 2*log2(e)
    z = fmin(fmax(z, -64.0), 64.0);                 // saturate: |tanh|=1 to 1e-19
    const double n = rint(z);
    const double f = z - n;                         // |f| <= 0.5
    // exp2(f) Taylor, degree 13: c_k = ln2^k / k!
    double p = 1.36248547315093758e-12;
    p = fma(p, f, 2.56784359934881958e-11);
    p = fma(p, f, 4.44553827187081007e-10);
    p = fma(p, f, 7.05491162080112087e-09);
    p = fma(p, f, 1.01780860092396960e-07);
    p = fma(p, f, 1.32154867901443094e-06);
    p = fma(p, f, 1.52527338040598403e-05);
    p = fma(p, f, 1.54035303933816099e-04);
    p = fma(p, f, 1.33335581464284434e-03);
    p = fma(p, f, 9.61812910762847716e-03);
    p = fma(p, f, 5.55041086648215800e-02);
    p = fma(p, f, 2.40226506959100712e-01);
    p = fma(p, f, 6.93147180559945309e-01);
    p = fma(p, f, 1.0);
    const long long eb = ((long long)(1023 + (int)n)) << 52;
    const double t = p * __longlong_as_double(eb);  // 2^z
    return 1.0 - 2.0 / (t + 1.0);
}

// ---------------- Kernel 1: fp64 MFMA GEMM with fused tanh input, dbuf LDS ----------------
// icq[t*16384 + b*1024 + e] = tanh(tanh(0.5 x) @ W^T) + noise*CNOISE + 1e-6  (fp64, t-major)
// R3 measured: FETCH 124 MB (swizzle works, HBM 4% of peak, bank conflicts 0),
// MfmaUtil 62%, Occupancy 21% (2 blocks/CU) -> barrier-tail bound, NOT memory.
// This round: W staged as f32 in LDS (f32->f64 convert at fragment read is EXACT,
// W values are f32 source data) -> LDS 69632->52224 B -> 3 blocks/CU; layout
// probe moved to epilogue + __launch_bounds__(256,3) to fit ~170 reg/wave.
#define BM 128
#define BN 128
#define BK 16
#define RS 17

__launch_bounds__(256, 3)
__global__ void k_gemm_tanh_mfma(const float* __restrict__ X, const float* __restrict__ W,
                                 const float* __restrict__ noise, double* __restrict__ icq) {
    __shared__ double As[2][BM][RS];  // [buf][m][k] fp64 (tanh values need fp64)
    __shared__ float  Bs[2][BN][RS];  // [buf][e][k] f32 (exact: W is f32 data)

    const int tid = threadIdx.x;
    const int l  = tid & 63;
    const int w  = tid >> 6;          // wave 0..3
    const int wm = (w & 1) * 64;      // wave m offset
    const int wn = (w >> 1) * 64;     // wave e offset
    const int lr = l & 15;            // M/N index within 16
    const int lg = l >> 4;            // K group 0..3

    // XCD-aware swizzle: round-robin dispatch puts bid%8 on the same XCD.
    // The 8 e-blocks sharing one A-panel land on one XCD -> A streamed from
    // HBM ~once per XCD (R3 measured: FETCH 124 MB, near-minimal).
    const int bid = blockIdx.x;
    const int xcd = bid & 7;
    const int q   = bid >> 3;              // 0..127 sequence within XCD
    const int m0 = ((q >> 3) * 8 + xcd) * BM;  // m-panel = mloc*8 + xcd
    const int e0 = (q & 7) * BN;               // e fastest within XCD

    // staging indices: thread covers rows sm+32i, col pair sc..sc+1
    const int sm = tid >> 3;        // 0..31
    const int sc = (tid & 7) * 2;   // 0,2,..,14

    v4d acc[4][4] = {};  // [mt][nt], 64x64 per wave

    // ---- Prologue: stage chunk 0 into buf 0 (scalar LDS stores: odd-stride rows) ----
#pragma unroll
    for (int i = 0; i < 4; ++i) {
        const int mrow = sm + 32 * i;
        const float2 fa = *(const float2*)&X[(size_t)(m0 + mrow) * DD + sc];
        As[0][mrow][sc]     = fast_tanh64((double)fa.x * 0.5);
        As[0][mrow][sc + 1] = fast_tanh64((double)fa.y * 0.5);
        const float2 f = *(const float2*)&W[(size_t)(e0 + mrow) * DD + sc];
        Bs[0][mrow][sc]     = f.x;
        Bs[0][mrow][sc + 1] = f.y;
    }
    __syncthreads();

    for (int kt = 0; kt < DD; kt += BK) {
        const int cur = (kt >> 4) & 1;
        const int nxt = cur ^ 1;
        const bool more = (kt + BK) < DD;

        // Issue next-chunk global loads BEFORE compute (latency hides under MFMA shadow)
        float2 pa[4]; float2 pb[4];
        if (more) {
#pragma unroll
            for (int i = 0; i < 4; ++i) {
                const int mrow = sm + 32 * i;
                pa[i] = *(const float2*)&X[(size_t)(m0 + mrow) * DD + kt + BK + sc];
                pb[i] = *(const float2*)&W[(size_t)(e0 + mrow) * DD + kt + BK + sc];
            }
        }

        // Compute: 4 s-iters x 16 MFMA = 64 MFMA per chunk per wave
#pragma unroll
        for (int s = 0; s < 4; ++s) {
            const int kk = 4 * s + lg;
            double a[4], b[4];
#pragma unroll
            for (int mt = 0; mt < 4; ++mt) a[mt] = As[cur][wm + 16 * mt + lr][kk];
#pragma unroll
            for (int nt = 0; nt < 4; ++nt) b[nt] = (double)Bs[cur][wn + 16 * nt + lr][kk];
#pragma unroll
            for (int mt = 0; mt < 4; ++mt)
#pragma unroll
                for (int nt = 0; nt < 4; ++nt)
                    acc[mt][nt] = __builtin_amdgcn_mfma_f64_16x16x4f64(a[mt], b[nt], acc[mt][nt], 0, 0, 0);
        }

        // Write prefetched chunk into the other buffer (tanh on A here, VALU pipe)
        if (more) {
#pragma unroll
            for (int i = 0; i < 4; ++i) {
                const int mrow = sm + 32 * i;
                As[nxt][mrow][sc]     = fast_tanh64((double)pa[i].x * 0.5);
                As[nxt][mrow][sc + 1] = fast_tanh64((double)pa[i].y * 0.5);
                Bs[nxt][mrow][sc]     = pb[i].x;
                Bs[nxt][mrow][sc + 1] = pb[i].y;
            }
        }
        __syncthreads();
    }

    // ---- Runtime C/D layout probe (moved here from prologue: its am/bn regs
    // no longer occupy VGPRs during the main loop -> fits 3-waves/SIMD budget) ----
    v4d zc = {};
    const double rowcode = (double)lr;
    v4d d1 = __builtin_amdgcn_mfma_f64_16x16x4f64(rowcode, 1.0, zc, 0, 0, 0);  // 4*row
    v4d d2 = __builtin_amdgcn_mfma_f64_16x16x4f64(1.0, rowcode, zc, 0, 0, 0);  // 4*col
    int am[4], bn[4];
#pragma unroll
    for (int ei = 0; ei < 4; ++ei) {
        am[ei] = ((int)d1[ei]) >> 2;
        bn[ei] = ((int)d2[ei]) >> 2;
    }

    // ---- Epilogue: icq = tanh(acc) + noise*c + 1e-6 (fp64), scatter t-major ----
#pragma unroll
    for (int mt = 0; mt < 4; ++mt) {
#pragma unroll
        for (int ei = 0; ei < 4; ++ei) {
            const int m = m0 + wm + 16 * mt + am[ei];
            const int b = m >> 10;       // m = b*TT + t
            const int t = m & 1023;
            const size_t rowbase = (size_t)(t * BB + b) * DD;
#pragma unroll
            for (int nt = 0; nt < 4; ++nt) {
                const int e = e0 + wn + 16 * nt + bn[ei];
                const double nq = (double)noise[(size_t)m * DD + e] * CNOISE + 1e-6;
                icq[rowbase + e] = fast_tanh64(acc[mt][nt][ei]) + nq;
            }
        }
    }
}

// ---------------- Kernel 2: fused serial LIF scan + output epilogue ----------------
// One thread per chain (b,e), iterating t. R3 post-mortem: WITHOUT launch_bounds
// hipcc assumes 1024-thr blocks -> VGPR cap 128; this kernel's ~170 regs of
// prefetch state (qc/qn 64 + nc/nn/xc/xn 64 + addressing) spilled to scratch,
// costing ~500 us instead of ~55. __launch_bounds__(64,1) -> 512-reg budget,
// zero spill. 256 blocks x 64 thr = 1 wave on each of 256 CUs; SCH=16 deep
// prefetch of icq+noise+x = 16 KB in flight/wave, 4 MB chip-wide ~ 4+ TB/s.
#define SCH 16

__device__ __forceinline__ float fast_tanhf(float v) {
    const float e = __expf(2.0f * v);
    return 1.0f - 2.0f / (e + 1.0f);
}

__launch_bounds__(64, 1)
__global__ void k_scan_out(const double* __restrict__ icq, const float* __restrict__ noise,
                           const float* __restrict__ x, const float* __restrict__ res_scale,
                           float* __restrict__ out) {
    const int tid = blockIdx.x * blockDim.x + threadIdx.x;  // chain id = b*1024+e
    const int b = tid >> 10;
    const int e = tid & 1023;
    const double* p = icq + tid;
    const size_t fbase = ((size_t)b << 20) + (size_t)e;     // (b,t,e) flat, t stride 1024

    const float rf = 1.0f / (1.0f + __expf(-res_scale[0]));
    const float omrf = 1.0f - rf;

    double qc[SCH], qn[SCH];
    float nc[SCH], nn[SCH], xc[SCH], xn[SCH];
#pragma unroll
    for (int i = 0; i < SCH; ++i) {
        qc[i] = p[(size_t)i * M_TOT];
        nc[i] = noise[fbase + ((size_t)i << 10)];
        xc[i] = x[fbase + ((size_t)i << 10)];
    }

    double mem = 0.0;
    for (int t0 = 0; t0 < TT; t0 += SCH) {
        const bool has_next = (t0 + SCH) < TT;
        if (has_next) {
#pragma unroll
            for (int i = 0; i < SCH; ++i) {
                const int t = t0 + SCH + i;
                qn[i] = p[(size_t)t * M_TOT];
                nn[i] = noise[fbase + ((size_t)t << 10)];
                xn[i] = x[fbase + ((size_t)t << 10)];
            }
        }
#pragma unroll
        for (int i = 0; i < SCH; ++i) {
            mem = fma(0.95, mem, qc[i]);        // icq already folds noise*c + 1e-6
            const bool s = (mem >= 0.15);
            // out = tanh((r*(s*ic*0.5) + (1-r)*tanh(0.5x)) * 0.5), all f32
            // (err ~1e-7 << tolerance; R3 passed absmax 1.95e-3)
            const float icf = (float)qc[i] - fmaf(nc[i], (float)CNOISE, 1e-6f);  // undo folded noise
            const float raw = s ? icf * 0.5f : 0.0f;
            const float xtt = fast_tanhf(0.5f * xc[i]);
            out[fbase + ((size_t)(t0 + i) << 10)] = fast_tanhf(fmaf(rf, raw, omrf * xtt) * 0.5f);
            mem = s ? -0.05 : mem;
        }
        if (has_next) {
#pragma unroll
            for (int i = 0; i < SCH; ++i) { qc[i] = qn[i]; nc[i] = nn[i]; xc[i] = xn[i]; }
        }
    }
}

// ---------------- Launch ----------------
extern "C" void kernel_launch(void* const* d_in, const int* in_sizes, int n_in,
                              void* d_out, int out_size, void* d_ws, size_t ws_size,
                              hipStream_t stream) {
    const float* x     = (const float*)d_in[0];   // (B,T,D) f32
    const float* W     = (const float*)d_in[1];   // (D,D) f32
    const float* rs    = (const float*)d_in[2];   // scalar f32
    const float* noise = (const float*)d_in[3];   // (B,T,D) f32
    float* out = (float*)d_out;

    // ws layout: icq (double, 16M) = 134 MB.
    double* icq = (double*)d_ws;

    k_gemm_tanh_mfma<<<(M_TOT / BM) * (DD / BN), 256, 0, stream>>>(x, W, noise, icq);

    k_scan_out<<<M_TOT / 64, 64, 0, stream>>>(icq, noise, x, rs, out);
}

// Round 5
// 942.688 us; speedup vs baseline: 2.5920x; 2.5920x over previous
//
#include <hip/hip_runtime.h>
#include <math.h>

// Problem constants (B,T,D) = (16,1024,1024)
#define BB 16
#define TT 1024
#define DD 1024
#define M_TOT (BB * TT)   // 16384 GEMM rows / LIF chains

typedef double v4d __attribute__((ext_vector_type(4)));
typedef double v2d __attribute__((ext_vector_type(2)));

#define CNOISE (0.005 * 0.15)   // NOISE_SCALE * THRESHOLD

// ---------------- Fast branch-free fp64 tanh ----------------
// tanh(y) = 1 - 2/(2^(y*2*log2(e)) + 1). Absolute error ~1e-15. Only ABSOLUTE
// ic accuracy (~1e-10) matters for spike thresholding. ~35 straight-line fp64
// ops vs libm's branchy ~80.
__device__ __forceinline__ double fast_tanh64(double y) {
    double z = y * 2.8853900817779268;              // 2*log2(e)
    z = fmin(fmax(z, -64.0), 64.0);                 // saturate: |tanh|=1 to 1e-19
    const double n = rint(z);
    const double f = z - n;                         // |f| <= 0.5
    // exp2(f) Taylor, degree 13: c_k = ln2^k / k!
    double p = 1.36248547315093758e-12;
    p = fma(p, f, 2.56784359934881958e-11);
    p = fma(p, f, 4.44553827187081007e-10);
    p = fma(p, f, 7.05491162080112087e-09);
    p = fma(p, f, 1.01780860092396960e-07);
    p = fma(p, f, 1.32154867901443094e-06);
    p = fma(p, f, 1.52527338040598403e-05);
    p = fma(p, f, 1.54035303933816099e-04);
    p = fma(p, f, 1.33335581464284434e-03);
    p = fma(p, f, 9.61812910762847716e-03);
    p = fma(p, f, 5.55041086648215800e-02);
    p = fma(p, f, 2.40226506959100712e-01);
    p = fma(p, f, 6.93147180559945309e-01);
    p = fma(p, f, 1.0);
    const long long eb = ((long long)(1023 + (int)n)) << 52;
    const double t = p * __longlong_as_double(eb);  // 2^z
    return 1.0 - 2.0 / (t + 1.0);
}

// ---------------- Kernel 1: fp64 MFMA GEMM with fused tanh input, dbuf LDS ----------------
// icq[t*16384 + b*1024 + e] = tanh(tanh(0.5 x) @ W^T) + noise*CNOISE + 1e-6  (fp64, t-major)
// EXACT R3 configuration (measured: 778 us, MfmaUtil 62%, FETCH 124 MB,
// bank conflicts 0, VGPR 112, occupancy 21% = 2 blocks/CU).
// R4 post-mortem: launch_bounds(256,3) spilled the 128-reg fp64 accumulator
// file (VGPR 84, 8.9 GB scratch traffic, 2300 us); f32 Bs broke the RS=17
// fp64 bank mapping (1.26e7 conflicts). Occupancy is structurally capped at
// 2 blocks/CU by acc[4][4] (16 x 8 regs) — do NOT raise min-waves.
#define BM 128
#define BN 128
#define BK 16
#define RS 17

__launch_bounds__(256, 2)
__global__ void k_gemm_tanh_mfma(const float* __restrict__ X, const float* __restrict__ W,
                                 const float* __restrict__ noise, double* __restrict__ icq) {
    __shared__ double As[2][BM][RS];  // [buf][m][k]
    __shared__ double Bs[2][BN][RS];  // [buf][e][k]

    const int tid = threadIdx.x;
    const int l  = tid & 63;
    const int w  = tid >> 6;          // wave 0..3
    const int wm = (w & 1) * 64;      // wave m offset
    const int wn = (w >> 1) * 64;     // wave e offset
    const int lr = l & 15;            // M/N index within 16
    const int lg = l >> 4;            // K group 0..3

    // XCD-aware swizzle: the 8 e-blocks sharing one A-panel land on one XCD
    // -> A streamed from HBM ~once per XCD (R3 measured: FETCH 124 MB).
    const int bid = blockIdx.x;
    const int xcd = bid & 7;
    const int q   = bid >> 3;              // 0..127 sequence within XCD
    const int m0 = ((q >> 3) * 8 + xcd) * BM;  // m-panel = mloc*8 + xcd
    const int e0 = (q & 7) * BN;               // e fastest within XCD

    // ---- Runtime C/D layout probe (2 MFMAs, negligible) ----
    v4d zc = {};
    const double rowcode = (double)lr;
    v4d d1 = __builtin_amdgcn_mfma_f64_16x16x4f64(rowcode, 1.0, zc, 0, 0, 0);  // 4*row
    v4d d2 = __builtin_amdgcn_mfma_f64_16x16x4f64(1.0, rowcode, zc, 0, 0, 0);  // 4*col
    int am[4], bn[4];
#pragma unroll
    for (int ei = 0; ei < 4; ++ei) {
        am[ei] = ((int)d1[ei]) >> 2;
        bn[ei] = ((int)d2[ei]) >> 2;
    }

    // staging indices: thread covers rows sm+32i, col pair sc..sc+1
    const int sm = tid >> 3;        // 0..31
    const int sc = (tid & 7) * 2;   // 0,2,..,14

    v4d acc[4][4] = {};  // [mt][nt], 64x64 per wave

    // ---- Prologue: stage chunk 0 into buf 0 (scalar LDS stores: odd-stride rows) ----
#pragma unroll
    for (int i = 0; i < 4; ++i) {
        const int mrow = sm + 32 * i;
        const float2 fa = *(const float2*)&X[(size_t)(m0 + mrow) * DD + sc];
        As[0][mrow][sc]     = fast_tanh64((double)fa.x * 0.5);
        As[0][mrow][sc + 1] = fast_tanh64((double)fa.y * 0.5);
        const float2 f = *(const float2*)&W[(size_t)(e0 + mrow) * DD + sc];
        Bs[0][mrow][sc]     = (double)f.x;
        Bs[0][mrow][sc + 1] = (double)f.y;
    }
    __syncthreads();

    for (int kt = 0; kt < DD; kt += BK) {
        const int cur = (kt >> 4) & 1;
        const int nxt = cur ^ 1;
        const bool more = (kt + BK) < DD;

        // Issue next-chunk global loads BEFORE compute (latency hides under MFMA shadow)
        float2 pa[4]; float2 pb[4];
        if (more) {
#pragma unroll
            for (int i = 0; i < 4; ++i) {
                const int mrow = sm + 32 * i;
                pa[i] = *(const float2*)&X[(size_t)(m0 + mrow) * DD + kt + BK + sc];
                pb[i] = *(const float2*)&W[(size_t)(e0 + mrow) * DD + kt + BK + sc];
            }
        }

        // Compute: 4 s-iters x 16 MFMA = 64 MFMA per chunk per wave
#pragma unroll
        for (int s = 0; s < 4; ++s) {
            const int kk = 4 * s + lg;
            double a[4], b[4];
#pragma unroll
            for (int mt = 0; mt < 4; ++mt) a[mt] = As[cur][wm + 16 * mt + lr][kk];
#pragma unroll
            for (int nt = 0; nt < 4; ++nt) b[nt] = Bs[cur][wn + 16 * nt + lr][kk];
#pragma unroll
            for (int mt = 0; mt < 4; ++mt)
#pragma unroll
                for (int nt = 0; nt < 4; ++nt)
                    acc[mt][nt] = __builtin_amdgcn_mfma_f64_16x16x4f64(a[mt], b[nt], acc[mt][nt], 0, 0, 0);
        }

        // Write prefetched chunk into the other buffer (tanh on A here, VALU pipe)
        if (more) {
#pragma unroll
            for (int i = 0; i < 4; ++i) {
                const int mrow = sm + 32 * i;
                As[nxt][mrow][sc]     = fast_tanh64((double)pa[i].x * 0.5);
                As[nxt][mrow][sc + 1] = fast_tanh64((double)pa[i].y * 0.5);
                Bs[nxt][mrow][sc]     = (double)pb[i].x;
                Bs[nxt][mrow][sc + 1] = (double)pb[i].y;
            }
        }
        __syncthreads();
    }

    // ---- Epilogue: icq = tanh(acc) + noise*c + 1e-6 (fp64), scatter t-major ----
#pragma unroll
    for (int mt = 0; mt < 4; ++mt) {
#pragma unroll
        for (int ei = 0; ei < 4; ++ei) {
            const int m = m0 + wm + 16 * mt + am[ei];
            const int b = m >> 10;       // m = b*TT + t
            const int t = m & 1023;
            const size_t rowbase = (size_t)(t * BB + b) * DD;
#pragma unroll
            for (int nt = 0; nt < 4; ++nt) {
                const int e = e0 + wn + 16 * nt + bn[ei];
                const double nq = (double)noise[(size_t)m * DD + e] * CNOISE + 1e-6;
                icq[rowbase + e] = fast_tanh64(acc[mt][nt][ei]) + nq;
            }
        }
    }
}

// ---------------- Kernel 2: fused serial LIF scan + output epilogue ----------------
// One thread per chain (b,e), iterating t. 16384 chains = 256 CU x 64 lanes ->
// hard cap 1 wave/CU, so BW comes from per-wave MLP depth. R4 measured ~140 us
// at SCH=16 (16 KB in flight/wave ~ 2.4 TB/s, latency-limited vs ~900cy HBM).
// SCH=32 -> 32 KB in flight/wave. VGPR ~280 (qc/qn 128 + f32 bufs 128 + addr),
// fits the 512-reg budget from __launch_bounds__(64,1); all indices are
// compile-time (full unroll) so no scratch (R3 spill lesson).
#define SCH 32

__device__ __forceinline__ float fast_tanhf(float v) {
    const float e = __expf(2.0f * v);
    return 1.0f - 2.0f / (e + 1.0f);
}

__launch_bounds__(64, 1)
__global__ void k_scan_out(const double* __restrict__ icq, const float* __restrict__ noise,
                           const float* __restrict__ x, const float* __restrict__ res_scale,
                           float* __restrict__ out) {
    const int tid = blockIdx.x * blockDim.x + threadIdx.x;  // chain id = b*1024+e
    const int b = tid >> 10;
    const int e = tid & 1023;
    const double* p = icq + tid;
    const size_t fbase = ((size_t)b << 20) + (size_t)e;     // (b,t,e) flat, t stride 1024

    const float rf = 1.0f / (1.0f + __expf(-res_scale[0]));
    const float omrf = 1.0f - rf;

    double qc[SCH], qn[SCH];
    float nc[SCH], nn[SCH], xc[SCH], xn[SCH];
#pragma unroll
    for (int i = 0; i < SCH; ++i) {
        qc[i] = p[(size_t)i * M_TOT];
        nc[i] = noise[fbase + ((size_t)i << 10)];
        xc[i] = x[fbase + ((size_t)i << 10)];
    }

    double mem = 0.0;
    for (int t0 = 0; t0 < TT; t0 += SCH) {
        const bool has_next = (t0 + SCH) < TT;
        if (has_next) {
#pragma unroll
            for (int i = 0; i < SCH; ++i) {
                const int t = t0 + SCH + i;
                qn[i] = p[(size_t)t * M_TOT];
                nn[i] = noise[fbase + ((size_t)t << 10)];
                xn[i] = x[fbase + ((size_t)t << 10)];
            }
        }
#pragma unroll
        for (int i = 0; i < SCH; ++i) {
            mem = fma(0.95, mem, qc[i]);        // icq already folds noise*c + 1e-6
            const bool s = (mem >= 0.15);
            // out = tanh((r*(s*ic*0.5) + (1-r)*tanh(0.5x)) * 0.5), all f32
            // (err ~1e-7 << tolerance; R3/R4 passed absmax 1.95e-3)
            const float icf = (float)qc[i] - fmaf(nc[i], (float)CNOISE, 1e-6f);  // undo folded noise
            const float raw = s ? icf * 0.5f : 0.0f;
            const float xtt = fast_tanhf(0.5f * xc[i]);
            out[fbase + ((size_t)(t0 + i) << 10)] = fast_tanhf(fmaf(rf, raw, omrf * xtt) * 0.5f);
            mem = s ? -0.05 : mem;
        }
        if (has_next) {
#pragma unroll
            for (int i = 0; i < SCH; ++i) { qc[i] = qn[i]; nc[i] = nn[i]; xc[i] = xn[i]; }
        }
    }
}

// ---------------- Launch ----------------
extern "C" void kernel_launch(void* const* d_in, const int* in_sizes, int n_in,
                              void* d_out, int out_size, void* d_ws, size_t ws_size,
                              hipStream_t stream) {
    const float* x     = (const float*)d_in[0];   // (B,T,D) f32
    const float* W     = (const float*)d_in[1];   // (D,D) f32
    const float* rs    = (const float*)d_in[2];   // scalar f32
    const float* noise = (const float*)d_in[3];   // (B,T,D) f32
    float* out = (float*)d_out;

    // ws layout: icq (double, 16M) = 134 MB.
    double* icq = (double*)d_ws;

    k_gemm_tanh_mfma<<<(M_TOT / BM) * (DD / BN), 256, 0, stream>>>(x, W, noise, icq);

    k_scan_out<<<M_TOT / 64, 64, 0, stream>>>(icq, noise, x, rs, out);
}

// Round 11
// 873.600 us; speedup vs baseline: 2.7970x; 1.0791x over previous
//
#include <hip/hip_runtime.h>
#include <math.h>

// Problem constants (B,T,D) = (16,1024,1024)
#define BB 16
#define TT 1024
#define DD 1024
#define M_TOT (BB * TT)   // 16384 GEMM rows / LIF chains

typedef double v4d __attribute__((ext_vector_type(4)));
typedef double v2d __attribute__((ext_vector_type(2)));

#define CNOISE (0.005 * 0.15)   // NOISE_SCALE * THRESHOLD

// ---------------- Fast branch-free fp64 tanh ----------------
// tanh(y) = 1 - 2/(2^(y*2*log2(e)) + 1). Absolute error ~1e-15. Only ABSOLUTE
// ic accuracy (~1e-10) matters for spike thresholding. ~35 straight-line fp64
// ops vs libm's branchy ~80.
__device__ __forceinline__ double fast_tanh64(double y) {
    double z = y * 2.8853900817779268;              // 2*log2(e)
    z = fmin(fmax(z, -64.0), 64.0);                 // saturate: |tanh|=1 to 1e-19
    const double n = rint(z);
    const double f = z - n;                         // |f| <= 0.5
    // exp2(f) Taylor, degree 13: c_k = ln2^k / k!
    double p = 1.36248547315093758e-12;
    p = fma(p, f, 2.56784359934881958e-11);
    p = fma(p, f, 4.44553827187081007e-10);
    p = fma(p, f, 7.05491162080112087e-09);
    p = fma(p, f, 1.01780860092396960e-07);
    p = fma(p, f, 1.32154867901443094e-06);
    p = fma(p, f, 1.52527338040598403e-05);
    p = fma(p, f, 1.54035303933816099e-04);
    p = fma(p, f, 1.33335581464284434e-03);
    p = fma(p, f, 9.61812910762847716e-03);
    p = fma(p, f, 5.55041086648215800e-02);
    p = fma(p, f, 2.40226506959100712e-01);
    p = fma(p, f, 6.93147180559945309e-01);
    p = fma(p, f, 1.0);
    const long long eb = ((long long)(1023 + (int)n)) << 52;
    const double t = p * __longlong_as_double(eb);  // 2^z
    return 1.0 - 2.0 / (t + 1.0);
}

// ---------------- Kernel 1: fp64 MFMA GEMM with fused tanh input, dbuf LDS ----------------
// icq[t*16384 + b*1024 + e] = tanh(tanh(0.5 x) @ W^T) + noise*CNOISE + 1e-6  (fp64, t-major)
// BANKED R3/R5 configuration (measured twice: 773-778 us, MfmaUtil 63.9%,
// FETCH 124 MB, bank conflicts 0, VGPR 112, occupancy 21.9% = 2 blocks/CU).
// R4 lesson: acc[4][4] = 128 VGPRs structurally caps at 2 blocks/CU; do NOT
// raise min-waves (spills acc -> 8.9 GB scratch). f32 Bs breaks RS=17 fp64
// bank mapping. DO NOT TOUCH without dedicated round.
#define BM 128
#define BN 128
#define BK 16
#define RS 17

__launch_bounds__(256, 2)
__global__ void k_gemm_tanh_mfma(const float* __restrict__ X, const float* __restrict__ W,
                                 const float* __restrict__ noise, double* __restrict__ icq) {
    __shared__ double As[2][BM][RS];  // [buf][m][k]
    __shared__ double Bs[2][BN][RS];  // [buf][e][k]

    const int tid = threadIdx.x;
    const int l  = tid & 63;
    const int w  = tid >> 6;          // wave 0..3
    const int wm = (w & 1) * 64;      // wave m offset
    const int wn = (w >> 1) * 64;     // wave e offset
    const int lr = l & 15;            // M/N index within 16
    const int lg = l >> 4;            // K group 0..3

    // XCD-aware swizzle: the 8 e-blocks sharing one A-panel land on one XCD
    // -> A streamed from HBM ~once per XCD (R3/R5 measured: FETCH 124 MB).
    const int bid = blockIdx.x;
    const int xcd = bid & 7;
    const int q   = bid >> 3;              // 0..127 sequence within XCD
    const int m0 = ((q >> 3) * 8 + xcd) * BM;  // m-panel = mloc*8 + xcd
    const int e0 = (q & 7) * BN;               // e fastest within XCD

    // ---- Runtime C/D layout probe (2 MFMAs, negligible) ----
    v4d zc = {};
    const double rowcode = (double)lr;
    v4d d1 = __builtin_amdgcn_mfma_f64_16x16x4f64(rowcode, 1.0, zc, 0, 0, 0);  // 4*row
    v4d d2 = __builtin_amdgcn_mfma_f64_16x16x4f64(1.0, rowcode, zc, 0, 0, 0);  // 4*col
    int am[4], bn[4];
#pragma unroll
    for (int ei = 0; ei < 4; ++ei) {
        am[ei] = ((int)d1[ei]) >> 2;
        bn[ei] = ((int)d2[ei]) >> 2;
    }

    // staging indices: thread covers rows sm+32i, col pair sc..sc+1
    const int sm = tid >> 3;        // 0..31
    const int sc = (tid & 7) * 2;   // 0,2,..,14

    v4d acc[4][4] = {};  // [mt][nt], 64x64 per wave

    // ---- Prologue: stage chunk 0 into buf 0 (scalar LDS stores: odd-stride rows) ----
#pragma unroll
    for (int i = 0; i < 4; ++i) {
        const int mrow = sm + 32 * i;
        const float2 fa = *(const float2*)&X[(size_t)(m0 + mrow) * DD + sc];
        As[0][mrow][sc]     = fast_tanh64((double)fa.x * 0.5);
        As[0][mrow][sc + 1] = fast_tanh64((double)fa.y * 0.5);
        const float2 f = *(const float2*)&W[(size_t)(e0 + mrow) * DD + sc];
        Bs[0][mrow][sc]     = (double)f.x;
        Bs[0][mrow][sc + 1] = (double)f.y;
    }
    __syncthreads();

    for (int kt = 0; kt < DD; kt += BK) {
        const int cur = (kt >> 4) & 1;
        const int nxt = cur ^ 1;
        const bool more = (kt + BK) < DD;

        // Issue next-chunk global loads BEFORE compute (latency hides under MFMA shadow)
        float2 pa[4]; float2 pb[4];
        if (more) {
#pragma unroll
            for (int i = 0; i < 4; ++i) {
                const int mrow = sm + 32 * i;
                pa[i] = *(const float2*)&X[(size_t)(m0 + mrow) * DD + kt + BK + sc];
                pb[i] = *(const float2*)&W[(size_t)(e0 + mrow) * DD + kt + BK + sc];
            }
        }

        // Compute: 4 s-iters x 16 MFMA = 64 MFMA per chunk per wave
#pragma unroll
        for (int s = 0; s < 4; ++s) {
            const int kk = 4 * s + lg;
            double a[4], b[4];
#pragma unroll
            for (int mt = 0; mt < 4; ++mt) a[mt] = As[cur][wm + 16 * mt + lr][kk];
#pragma unroll
            for (int nt = 0; nt < 4; ++nt) b[nt] = Bs[cur][wn + 16 * nt + lr][kk];
#pragma unroll
            for (int mt = 0; mt < 4; ++mt)
#pragma unroll
                for (int nt = 0; nt < 4; ++nt)
                    acc[mt][nt] = __builtin_amdgcn_mfma_f64_16x16x4f64(a[mt], b[nt], acc[mt][nt], 0, 0, 0);
        }

        // Write prefetched chunk into the other buffer (tanh on A here, VALU pipe)
        if (more) {
#pragma unroll
            for (int i = 0; i < 4; ++i) {
                const int mrow = sm + 32 * i;
                As[nxt][mrow][sc]     = fast_tanh64((double)pa[i].x * 0.5);
                As[nxt][mrow][sc + 1] = fast_tanh64((double)pa[i].y * 0.5);
                Bs[nxt][mrow][sc]     = (double)pb[i].x;
                Bs[nxt][mrow][sc + 1] = (double)pb[i].y;
            }
        }
        __syncthreads();
    }

    // ---- Epilogue: icq = tanh(acc) + noise*c + 1e-6 (fp64), scatter t-major ----
#pragma unroll
    for (int mt = 0; mt < 4; ++mt) {
#pragma unroll
        for (int ei = 0; ei < 4; ++ei) {
            const int m = m0 + wm + 16 * mt + am[ei];
            const int b = m >> 10;       // m = b*TT + t
            const int t = m & 1023;
            const size_t rowbase = (size_t)(t * BB + b) * DD;
#pragma unroll
            for (int nt = 0; nt < 4; ++nt) {
                const int e = e0 + wn + 16 * nt + bn[ei];
                const double nq = (double)noise[(size_t)m * DD + e] * CNOISE + 1e-6;
                icq[rowbase + e] = fast_tanh64(acc[mt][nt][ei]) + nq;
            }
        }
    }
}

// ---------------- Kernel 2: EXACT staggered-segment LIF scan + output epilogue ----------------
// R6 post-mortem: 96-step coalescence warm-up FAILED absmax (7.3e-2): divergent
// spikes ping-pong (reset one drops to -0.05, other stays near threshold),
// so P(not coalesced) ~1e-5 per boundary x 49k boundaries = spike flips.
// Lesson: use the EXACT construction. Segment s replays [0, 256s) icq-only
// from the TRUE initial state (mem=0 at t=0), then writes its quarter
// [256s, 256(s+1)) -> mem is bit-identical to the serial scan for every
// output. No statistics.
// TLP: 4 staggered waves/CU (loads 16/32/48/64 batches) overlap each other's
// vmcnt drains (R5's 1-wave/CU structure exposed them fully -> 169 us);
// short waves finish early and free BW for the long ones.
#define SSEG 4
#define SEGT (TT / SSEG)   // 256
#define SCH 16             // main-phase prefetch depth
#define SCHW 32            // warm-up prefetch depth (icq-only, regs free then)

__device__ __forceinline__ float fast_tanhf(float v) {
    const float e = __expf(2.0f * v);
    return 1.0f - 2.0f / (e + 1.0f);
}

__launch_bounds__(64, 1)
__global__ void k_scan_out(const double* __restrict__ icq, const float* __restrict__ noise,
                           const float* __restrict__ x, const float* __restrict__ res_scale,
                           float* __restrict__ out) {
    const int cb  = blockIdx.x & 255;              // chain-block 0..255
    const int seg = blockIdx.x >> 8;               // segment 0..3
    const int tid = cb * 64 + threadIdx.x;         // chain id = b*1024+e
    const int b = tid >> 10;
    const int e = tid & 1023;
    const double* p = icq + tid;
    const size_t fbase = ((size_t)b << 20) + (size_t)e;   // (b,t,e) flat, t stride 1024

    const float rf = 1.0f / (1.0f + __expf(-res_scale[0]));
    const float omrf = 1.0f - rf;

    const int t_start = seg * SEGT;
    double mem = 0.0;

    // ---- EXACT warm-up: replay [0, t_start) icq-only, dbuf SCHW=32 ----
    if (seg) {
        double wc[SCHW], wn2[SCHW];
#pragma unroll
        for (int i = 0; i < SCHW; ++i) wc[i] = p[(size_t)i * M_TOT];
        for (int tw = 0; tw < t_start; tw += SCHW) {
            const bool more = (tw + SCHW) < t_start;
            if (more) {
#pragma unroll
                for (int i = 0; i < SCHW; ++i) wn2[i] = p[(size_t)(tw + SCHW + i) * M_TOT];
            }
#pragma unroll
            for (int i = 0; i < SCHW; ++i) {
                mem = fma(0.95, mem, wc[i]);
                mem = (mem >= 0.15) ? -0.05 : mem;
            }
            if (more) {
#pragma unroll
                for (int i = 0; i < SCHW; ++i) wc[i] = wn2[i];
            }
        }
    }

    // ---- Main: 256 steps with outputs, double-buffered SCH=16 prefetch ----
    double qc[SCH], qn[SCH];
    float nc[SCH], nn[SCH], xc[SCH], xn[SCH];
#pragma unroll
    for (int i = 0; i < SCH; ++i) {
        qc[i] = p[(size_t)(t_start + i) * M_TOT];
        nc[i] = noise[fbase + ((size_t)(t_start + i) << 10)];
        xc[i] = x[fbase + ((size_t)(t_start + i) << 10)];
    }

    for (int t0 = t_start; t0 < t_start + SEGT; t0 += SCH) {
        const bool has_next = (t0 + SCH) < (t_start + SEGT);
        if (has_next) {
#pragma unroll
            for (int i = 0; i < SCH; ++i) {
                const int t = t0 + SCH + i;
                qn[i] = p[(size_t)t * M_TOT];
                nn[i] = noise[fbase + ((size_t)t << 10)];
                xn[i] = x[fbase + ((size_t)t << 10)];
            }
        }
#pragma unroll
        for (int i = 0; i < SCH; ++i) {
            mem = fma(0.95, mem, qc[i]);        // icq already folds noise*c + 1e-6
            const bool s = (mem >= 0.15);
            // out = tanh((r*(s*ic*0.5) + (1-r)*tanh(0.5x)) * 0.5), all f32
            // (err ~1e-7 << tolerance; R3/R4/R5 passed absmax 1.95e-3)
            const float icf = (float)qc[i] - fmaf(nc[i], (float)CNOISE, 1e-6f);  // undo folded noise
            const float raw = s ? icf * 0.5f : 0.0f;
            const float xtt = fast_tanhf(0.5f * xc[i]);
            out[fbase + ((size_t)(t0 + i) << 10)] = fast_tanhf(fmaf(rf, raw, omrf * xtt) * 0.5f);
            mem = s ? -0.05 : mem;
        }
        if (has_next) {
#pragma unroll
            for (int i = 0; i < SCH; ++i) { qc[i] = qn[i]; nc[i] = nn[i]; xc[i] = xn[i]; }
        }
    }
}

// ---------------- Launch ----------------
extern "C" void kernel_launch(void* const* d_in, const int* in_sizes, int n_in,
                              void* d_out, int out_size, void* d_ws, size_t ws_size,
                              hipStream_t stream) {
    const float* x     = (const float*)d_in[0];   // (B,T,D) f32
    const float* W     = (const float*)d_in[1];   // (D,D) f32
    const float* rs    = (const float*)d_in[2];   // scalar f32
    const float* noise = (const float*)d_in[3];   // (B,T,D) f32
    float* out = (float*)d_out;

    // ws layout: icq (double, 16M) = 134 MB.
    double* icq = (double*)d_ws;

    k_gemm_tanh_mfma<<<(M_TOT / BM) * (DD / BN), 256, 0, stream>>>(x, W, noise, icq);

    k_scan_out<<<SSEG * (M_TOT / 64), 64, 0, stream>>>(icq, noise, x, rs, out);
}

// Round 12
// 800.260 us; speedup vs baseline: 3.0533x; 1.0916x over previous
//
#include <hip/hip_runtime.h>
#include <math.h>

// Problem constants (B,T,D) = (16,1024,1024)
#define BB 16
#define TT 1024
#define DD 1024
#define M_TOT (BB * TT)   // 16384 GEMM rows / LIF chains

typedef double v4d __attribute__((ext_vector_type(4)));
typedef double v2d __attribute__((ext_vector_type(2)));

#define CNOISE (0.005 * 0.15)   // NOISE_SCALE * THRESHOLD

// ---------------- Fast branch-free fp64 tanh ----------------
// tanh(y) = 1 - 2/(2^(y*2*log2(e)) + 1). Absolute error ~1e-15. Only ABSOLUTE
// ic accuracy (~1e-10) matters for spike thresholding. ~35 straight-line fp64
// ops vs libm's branchy ~80.
__device__ __forceinline__ double fast_tanh64(double y) {
    double z = y * 2.8853900817779268;              // 2*log2(e)
    z = fmin(fmax(z, -64.0), 64.0);                 // saturate: |tanh|=1 to 1e-19
    const double n = rint(z);
    const double f = z - n;                         // |f| <= 0.5
    // exp2(f) Taylor, degree 13: c_k = ln2^k / k!
    double p = 1.36248547315093758e-12;
    p = fma(p, f, 2.56784359934881958e-11);
    p = fma(p, f, 4.44553827187081007e-10);
    p = fma(p, f, 7.05491162080112087e-09);
    p = fma(p, f, 1.01780860092396960e-07);
    p = fma(p, f, 1.32154867901443094e-06);
    p = fma(p, f, 1.52527338040598403e-05);
    p = fma(p, f, 1.54035303933816099e-04);
    p = fma(p, f, 1.33335581464284434e-03);
    p = fma(p, f, 9.61812910762847716e-03);
    p = fma(p, f, 5.55041086648215800e-02);
    p = fma(p, f, 2.40226506959100712e-01);
    p = fma(p, f, 6.93147180559945309e-01);
    p = fma(p, f, 1.0);
    const long long eb = ((long long)(1023 + (int)n)) << 52;
    const double t = p * __longlong_as_double(eb);  // 2^z
    return 1.0 - 2.0 / (t + 1.0);
}

// ---------------- Kernel 1: xt = tanh(0.5 x) in fp64 (UN-FUSED from GEMM) ----------------
// R11 post-mortem: fused tanh staging put 27.5% VALUBusy on the GEMM's SIMDs;
// with 2 lockstep waves/SIMD that VALU issue DISPLACES MFMA issue (Mfma 63 +
// VALU 27 = 91% saturated). Un-fusing trades ~40 us of memory-bound k1
// (201 MB @ ~5.5 TB/s) for the GEMM's VALU headroom. fp64 xt needed: A-input
// error must stay ~1e-15 abs so accumulated ic error << spike-flip scale.
__global__ void k_tanh_xt(const float* __restrict__ x, double* __restrict__ xt) {
    const size_t i = ((size_t)blockIdx.x * blockDim.x + threadIdx.x) * 4;
    const float4 v = *(const float4*)(x + i);
    xt[i + 0] = fast_tanh64((double)v.x * 0.5);
    xt[i + 1] = fast_tanh64((double)v.y * 0.5);
    xt[i + 2] = fast_tanh64((double)v.z * 0.5);
    xt[i + 3] = fast_tanh64((double)v.w * 0.5);
}

// ---------------- Kernel 2: fp64 MFMA GEMM, dbuf LDS, 64x64 wave tile ----------------
// icq[t*16384 + b*1024 + e] = tanh(xt @ W^T) + noise*CNOISE + 1e-6  (fp64, t-major)
// Structure banked R3/R5/R11 (MfmaUtil 63%, FETCH 124 MB, conflicts 0, VGPR
// 112, 2 blocks/CU) MINUS the staging tanh (this round's single change).
// R4 lesson: acc[4][4] = 128 VGPRs caps at 2 blocks/CU; do NOT raise
// min-waves. f32 Bs breaks RS=17 fp64 bank mapping (1.26e7 conflicts).
#define BM 128
#define BN 128
#define BK 16
#define RS 17

__launch_bounds__(256, 2)
__global__ void k_gemm_tanh_mfma(const double* __restrict__ A, const float* __restrict__ W,
                                 const float* __restrict__ noise, double* __restrict__ icq) {
    __shared__ double As[2][BM][RS];  // [buf][m][k]
    __shared__ double Bs[2][BN][RS];  // [buf][e][k]

    const int tid = threadIdx.x;
    const int l  = tid & 63;
    const int w  = tid >> 6;          // wave 0..3
    const int wm = (w & 1) * 64;      // wave m offset
    const int wn = (w >> 1) * 64;     // wave e offset
    const int lr = l & 15;            // M/N index within 16
    const int lg = l >> 4;            // K group 0..3

    // XCD-aware swizzle: the 8 e-blocks sharing one A-panel land on one XCD
    // -> A streamed from HBM ~once per XCD (R3/R5/R11: FETCH minimal).
    const int bid = blockIdx.x;
    const int xcd = bid & 7;
    const int q   = bid >> 3;              // 0..127 sequence within XCD
    const int m0 = ((q >> 3) * 8 + xcd) * BM;  // m-panel = mloc*8 + xcd
    const int e0 = (q & 7) * BN;               // e fastest within XCD

    // ---- Runtime C/D layout probe (2 MFMAs, negligible) ----
    v4d zc = {};
    const double rowcode = (double)lr;
    v4d d1 = __builtin_amdgcn_mfma_f64_16x16x4f64(rowcode, 1.0, zc, 0, 0, 0);  // 4*row
    v4d d2 = __builtin_amdgcn_mfma_f64_16x16x4f64(1.0, rowcode, zc, 0, 0, 0);  // 4*col
    int am[4], bn[4];
#pragma unroll
    for (int ei = 0; ei < 4; ++ei) {
        am[ei] = ((int)d1[ei]) >> 2;
        bn[ei] = ((int)d2[ei]) >> 2;
    }

    // staging indices: thread covers rows sm+32i, col pair sc..sc+1
    const int sm = tid >> 3;        // 0..31
    const int sc = (tid & 7) * 2;   // 0,2,..,14

    v4d acc[4][4] = {};  // [mt][nt], 64x64 per wave

    // ---- Prologue: stage chunk 0 into buf 0 (scalar LDS stores: odd-stride rows) ----
#pragma unroll
    for (int i = 0; i < 4; ++i) {
        const int mrow = sm + 32 * i;
        const v2d a2 = *(const v2d*)&A[(size_t)(m0 + mrow) * DD + sc];
        As[0][mrow][sc]     = a2[0];
        As[0][mrow][sc + 1] = a2[1];
        const float2 f = *(const float2*)&W[(size_t)(e0 + mrow) * DD + sc];
        Bs[0][mrow][sc]     = (double)f.x;
        Bs[0][mrow][sc + 1] = (double)f.y;
    }
    __syncthreads();

    for (int kt = 0; kt < DD; kt += BK) {
        const int cur = (kt >> 4) & 1;
        const int nxt = cur ^ 1;
        const bool more = (kt + BK) < DD;

        // Issue next-chunk global loads BEFORE compute (latency hides under MFMA shadow)
        v2d pa[4]; float2 pb[4];
        if (more) {
#pragma unroll
            for (int i = 0; i < 4; ++i) {
                const int mrow = sm + 32 * i;
                pa[i] = *(const v2d*)&A[(size_t)(m0 + mrow) * DD + kt + BK + sc];
                pb[i] = *(const float2*)&W[(size_t)(e0 + mrow) * DD + kt + BK + sc];
            }
        }

        // Compute: 4 s-iters x 16 MFMA = 64 MFMA per chunk per wave
#pragma unroll
        for (int s = 0; s < 4; ++s) {
            const int kk = 4 * s + lg;
            double a[4], b[4];
#pragma unroll
            for (int mt = 0; mt < 4; ++mt) a[mt] = As[cur][wm + 16 * mt + lr][kk];
#pragma unroll
            for (int nt = 0; nt < 4; ++nt) b[nt] = Bs[cur][wn + 16 * nt + lr][kk];
#pragma unroll
            for (int mt = 0; mt < 4; ++mt)
#pragma unroll
                for (int nt = 0; nt < 4; ++nt)
                    acc[mt][nt] = __builtin_amdgcn_mfma_f64_16x16x4f64(a[mt], b[nt], acc[mt][nt], 0, 0, 0);
        }

        // Write prefetched chunk into the other buffer (pure data movement now)
        if (more) {
#pragma unroll
            for (int i = 0; i < 4; ++i) {
                const int mrow = sm + 32 * i;
                As[nxt][mrow][sc]     = pa[i][0];
                As[nxt][mrow][sc + 1] = pa[i][1];
                Bs[nxt][mrow][sc]     = (double)pb[i].x;
                Bs[nxt][mrow][sc + 1] = (double)pb[i].y;
            }
        }
        __syncthreads();
    }

    // ---- Epilogue: icq = tanh(acc) + noise*c + 1e-6 (fp64), scatter t-major ----
#pragma unroll
    for (int mt = 0; mt < 4; ++mt) {
#pragma unroll
        for (int ei = 0; ei < 4; ++ei) {
            const int m = m0 + wm + 16 * mt + am[ei];
            const int b = m >> 10;       // m = b*TT + t
            const int t = m & 1023;
            const size_t rowbase = (size_t)(t * BB + b) * DD;
#pragma unroll
            for (int nt = 0; nt < 4; ++nt) {
                const int e = e0 + wn + 16 * nt + bn[ei];
                const double nq = (double)noise[(size_t)m * DD + e] * CNOISE + 1e-6;
                icq[rowbase + e] = fast_tanh64(acc[mt][nt][ei]) + nq;
            }
        }
    }
}

// ---------------- Kernel 3: EXACT staggered-segment LIF scan + output epilogue ----------------
// BANKED R11: scan ~96 us (from 169 serial). Segment s replays [0, 256s)
// icq-only from the TRUE initial state (mem=0 at t=0), then writes its
// quarter [256s, 256(s+1)) -> mem bit-identical to the serial scan. 4
// staggered waves/CU overlap each other's vmcnt drains. (R6's statistical
// 96-step warm-up FAILED absmax 7.3e-2 — exact construction only.)
#define SSEG 4
#define SEGT (TT / SSEG)   // 256
#define SCH 16             // main-phase prefetch depth
#define SCHW 32            // warm-up prefetch depth (icq-only, regs free then)

__device__ __forceinline__ float fast_tanhf(float v) {
    const float e = __expf(2.0f * v);
    return 1.0f - 2.0f / (e + 1.0f);
}

__launch_bounds__(64, 1)
__global__ void k_scan_out(const double* __restrict__ icq, const float* __restrict__ noise,
                           const float* __restrict__ x, const float* __restrict__ res_scale,
                           float* __restrict__ out) {
    const int cb  = blockIdx.x & 255;              // chain-block 0..255
    const int seg = blockIdx.x >> 8;               // segment 0..3
    const int tid = cb * 64 + threadIdx.x;         // chain id = b*1024+e
    const int b = tid >> 10;
    const int e = tid & 1023;
    const double* p = icq + tid;
    const size_t fbase = ((size_t)b << 20) + (size_t)e;   // (b,t,e) flat, t stride 1024

    const float rf = 1.0f / (1.0f + __expf(-res_scale[0]));
    const float omrf = 1.0f - rf;

    const int t_start = seg * SEGT;
    double mem = 0.0;

    // ---- EXACT warm-up: replay [0, t_start) icq-only, dbuf SCHW=32 ----
    if (seg) {
        double wc[SCHW], wn2[SCHW];
#pragma unroll
        for (int i = 0; i < SCHW; ++i) wc[i] = p[(size_t)i * M_TOT];
        for (int tw = 0; tw < t_start; tw += SCHW) {
            const bool more = (tw + SCHW) < t_start;
            if (more) {
#pragma unroll
                for (int i = 0; i < SCHW; ++i) wn2[i] = p[(size_t)(tw + SCHW + i) * M_TOT];
            }
#pragma unroll
            for (int i = 0; i < SCHW; ++i) {
                mem = fma(0.95, mem, wc[i]);
                mem = (mem >= 0.15) ? -0.05 : mem;
            }
            if (more) {
#pragma unroll
                for (int i = 0; i < SCHW; ++i) wc[i] = wn2[i];
            }
        }
    }

    // ---- Main: 256 steps with outputs, double-buffered SCH=16 prefetch ----
    double qc[SCH], qn[SCH];
    float nc[SCH], nn[SCH], xc[SCH], xn[SCH];
#pragma unroll
    for (int i = 0; i < SCH; ++i) {
        qc[i] = p[(size_t)(t_start + i) * M_TOT];
        nc[i] = noise[fbase + ((size_t)(t_start + i) << 10)];
        xc[i] = x[fbase + ((size_t)(t_start + i) << 10)];
    }

    for (int t0 = t_start; t0 < t_start + SEGT; t0 += SCH) {
        const bool has_next = (t0 + SCH) < (t_start + SEGT);
        if (has_next) {
#pragma unroll
            for (int i = 0; i < SCH; ++i) {
                const int t = t0 + SCH + i;
                qn[i] = p[(size_t)t * M_TOT];
                nn[i] = noise[fbase + ((size_t)t << 10)];
                xn[i] = x[fbase + ((size_t)t << 10)];
            }
        }
#pragma unroll
        for (int i = 0; i < SCH; ++i) {
            mem = fma(0.95, mem, qc[i]);        // icq already folds noise*c + 1e-6
            const bool s = (mem >= 0.15);
            // out = tanh((r*(s*ic*0.5) + (1-r)*tanh(0.5x)) * 0.5), all f32
            // (err ~1e-7 << tolerance; passed absmax 1.95e-3 in R3/R5/R11)
            const float icf = (float)qc[i] - fmaf(nc[i], (float)CNOISE, 1e-6f);  // undo folded noise
            const float raw = s ? icf * 0.5f : 0.0f;
            const float xtt = fast_tanhf(0.5f * xc[i]);
            out[fbase + ((size_t)(t0 + i) << 10)] = fast_tanhf(fmaf(rf, raw, omrf * xtt) * 0.5f);
            mem = s ? -0.05 : mem;
        }
        if (has_next) {
#pragma unroll
            for (int i = 0; i < SCH; ++i) { qc[i] = qn[i]; nc[i] = nn[i]; xc[i] = xn[i]; }
        }
    }
}

// ---------------- Launch ----------------
extern "C" void kernel_launch(void* const* d_in, const int* in_sizes, int n_in,
                              void* d_out, int out_size, void* d_ws, size_t ws_size,
                              hipStream_t stream) {
    const float* x     = (const float*)d_in[0];   // (B,T,D) f32
    const float* W     = (const float*)d_in[1];   // (D,D) f32
    const float* rs    = (const float*)d_in[2];   // scalar f32
    const float* noise = (const float*)d_in[3];   // (B,T,D) f32
    float* out = (float*)d_out;

    // ws layout: xt (double, 16M) | icq (double, 16M) = 256 MB.
    double* xt  = (double*)d_ws;
    double* icq = xt + (size_t)M_TOT * DD;

    k_tanh_xt<<<(M_TOT * DD) / (256 * 4), 256, 0, stream>>>(x, xt);

    k_gemm_tanh_mfma<<<(M_TOT / BM) * (DD / BN), 256, 0, stream>>>(xt, W, noise, icq);

    k_scan_out<<<SSEG * (M_TOT / 64), 64, 0, stream>>>(icq, noise, x, rs, out);
}